// Round 2
// baseline (624.398 us; speedup 1.0000x reference)
//
#include <hip/hip_runtime.h>
#include <hip/hip_fp16.h>

// GridEncoder (instant-NGP triplane hash grid), static config:
//   D=3, L=3, C=2, base_res=128, per_level_scale=2, hashmap=2^19,
//   align_corners=False, linear interp, B=2^21.
// All levels hash-index; hmap=2^19 -> mod == & 0x7FFFF.
//
// R1: naive fp32 -> kernel 543 us, total 587 -> fixed harness overhead ~43.
// R2: half2 table + 3 level passes -> 62 us/pass @ 8 req/pt = 270 G req/s
//     (2 MB level table L2-resident).
// R4: fused 24x4B -> 175 us (203 G req/s).  R5: all-16B quads -> 184 us.
// R6/R7: mixed-width pair loads (15 req/pt floor for this layout class).
// R8: level-clustered fused gather, 2048 blocks x PPT=4 -> gather 127 us
//     @ 248 G req/s, FETCH 110 MB vs ~72 MB compulsory: VGPR=108 caps
//     residency at 1024 blocks -> TWO cohorts run different levels
//     concurrently -> 4 MB active set thrashes the 4 MiB/XCD L2.
// R9: FULL-GRID CO-RESIDENCY: 1024 blocks x PPT=8, __launch_bounds__(256,4)
//     (VGPR<=128 -> exactly 4 blocks/CU -> all 1024 co-resident) so every
//     resident wave is on the SAME level (2 MB active set, L2-resident).
//     Unified load path: one 16B quad at P&~3 always (holds e0, and e1 when
//     d<=3, 75% of lanes); single short arm of 4B partner loads for d>=7
//     (same 64B line for d<=15 -> MSHR-merged). Requests stay at the
//     15/pt floor; one divergent arm instead of three.
//     (R9 first attempt failed to compile: __builtin_nontemporal_load
//     rejects HIP_vector_type float4 -> use clang ext_vector float4.)

#define NPOINTS  2097152
#define HMASK    0x7FFFFu
#define PLANE    524288            // entries per level table
#define NTAB     (3 * PLANE)       // packed half2 entries (6 MB)
#define GBLOCKS  1024
#define TTHREADS (GBLOCKS * 256)   // 262144
#define PPT      8                 // points per thread

typedef float    floatx2 __attribute__((ext_vector_type(2)));
typedef float    floatx4 __attribute__((ext_vector_type(4)));
typedef unsigned uintx2  __attribute__((ext_vector_type(2)));
typedef unsigned uintx4  __attribute__((ext_vector_type(4)));

__device__ __forceinline__ unsigned pack2(float a, float b) {
    const __half2 h2 = __halves2half2(__float2half_rn(a), __float2half_rn(b));
    return *reinterpret_cast<const unsigned*>(&h2);
}

// ---- prepass: tbl[level*2^19 + h] = half2(b[h], b[PLANE+h]) ----
__global__ __launch_bounds__(256) void tp_convert_kernel(
    const float* __restrict__ tp, uintx4* __restrict__ tbl)
{
    const unsigned t = blockIdx.x * 256u + threadIdx.x;   // < NTAB/4
    const unsigned level = t >> 17;                       // 2^17 quads/level
    const unsigned i4    = (t & 131071u) << 2;
    const float* __restrict__ b = tp + level * (2u * PLANE);
    const floatx4 c0 = __builtin_nontemporal_load(
        reinterpret_cast<const floatx4*>(b + i4));
    const floatx4 c1 = __builtin_nontemporal_load(
        reinterpret_cast<const floatx4*>(b + PLANE + i4));
    uintx4 o;
    o.x = pack2(c0.x, c1.x);
    o.y = pack2(c0.y, c1.y);
    o.z = pack2(c0.z, c1.z);
    o.w = pack2(c0.w, c1.w);
    tbl[t] = o;
}

__device__ __forceinline__ unsigned sel4(uintx4 q, unsigned o) {
    const unsigned a = (o & 1u) ? q.y : q.x;
    const unsigned b = (o & 1u) ? q.w : q.z;
    return (o & 2u) ? b : a;
}

// ---- level-clustered fused gather, fully co-resident grid ----
__global__ __launch_bounds__(256, 4) void grid_gather_kernel(
    const unsigned* __restrict__ tbl,
    const float* __restrict__ inputs,
    floatx2* __restrict__ out)
{
    const int t = blockIdx.x * 256 + threadIdx.x;

    float x0[PPT], y0[PPT], z0[PPT];
#pragma unroll
    for (int p = 0; p < PPT; ++p) {
        const int i = t + p * TTHREADS;
        const float x = __builtin_nontemporal_load(&inputs[3 * i + 0]);
        const float y = __builtin_nontemporal_load(&inputs[3 * i + 1]);
        const float z = __builtin_nontemporal_load(&inputs[3 * i + 2]);
        x0[p] = (x + 1.0f) * 0.5f;
        y0[p] = (y + 1.0f) * 0.5f;
        z0[p] = (z + 1.0f) * 0.5f;
    }

    float o0[PPT], o1[PPT];
#pragma unroll
    for (int p = 0; p < PPT; ++p) { o0[p] = 0.0f; o1[p] = 0.0f; }

#pragma unroll
    for (int level = 0; level < 3; ++level) {
        const float scale = (float)((128 << level) - 1);  // 127, 255, 511
        const unsigned lvl = (unsigned)level << 19;

#pragma unroll
        for (int p = 0; p < PPT; ++p) {
            const float px = fmaf(x0[p], scale, 0.5f);
            const float py = fmaf(y0[p], scale, 0.5f);
            const float pz = fmaf(z0[p], scale, 0.5f);
            const float fx = floorf(px), fy = floorf(py), fz = floorf(pz);
            const float rx = px - fx, ry = py - fy, rz = pz - fz;
            const unsigned gx = (unsigned)fx, gy = (unsigned)fy, gz = (unsigned)fz;

            const unsigned d = gx ^ (gx + 1u);            // 1,3,7,15,...
            const unsigned hy0 = gy * 2654435761u;
            const unsigned hy1 = (gy + 1u) * 2654435761u;
            const unsigned hz0 = gz * 805459861u;
            const unsigned hz1 = (gz + 1u) * 805459861u;

            unsigned P[4];
            P[0] = lvl | ((gx ^ hy0 ^ hz0) & HMASK);
            P[1] = lvl | ((gx ^ hy1 ^ hz0) & HMASK);
            P[2] = lvl | ((gx ^ hy0 ^ hz1) & HMASK);
            P[3] = lvl | ((gx ^ hy1 ^ hz1) & HMASK);

            // unconditional: aligned 16B quad containing e0 (and e1 if d<=3)
            uintx4 q[4];
#pragma unroll
            for (int j = 0; j < 4; ++j)
                q[j] = *reinterpret_cast<const uintx4*>(tbl + (P[j] & ~3u));

            // interp weights (VALU overlaps with loads in flight)
            const float wx1 = rx, wx0 = 1.0f - rx;
            const float wy1 = ry, wy0 = 1.0f - ry;
            const float wz1 = rz, wz0 = 1.0f - rz;
            const float wyz[4] = { wy0 * wz0, wy1 * wz0, wy0 * wz1, wy1 * wz1 };

            unsigned e1v[4];
            if (d > 3u) {
                // distant partner: 4B loads (same 64B line as quad for d<=15)
#pragma unroll
                for (int j = 0; j < 4; ++j) e1v[j] = tbl[P[j] ^ d];
            } else {
                // partner inside the quad
#pragma unroll
                for (int j = 0; j < 4; ++j) e1v[j] = sel4(q[j], (P[j] & 3u) ^ d);
            }

#pragma unroll
            for (int j = 0; j < 4; ++j) {
                const unsigned e0 = sel4(q[j], P[j] & 3u);
                const __half2 a = *reinterpret_cast<const __half2*>(&e0);
                const __half2 b = *reinterpret_cast<const __half2*>(&e1v[j]);
                const float2 fa = __half22float2(a);
                const float2 fb = __half22float2(b);
                const float wA = wx0 * wyz[j], wB = wx1 * wyz[j];
                o0[p] = fmaf(wA, fa.x, o0[p]); o1[p] = fmaf(wA, fa.y, o1[p]);
                o0[p] = fmaf(wB, fb.x, o0[p]); o1[p] = fmaf(wB, fb.y, o1[p]);
            }
        }
        // phase alignment: ALL blocks are co-resident (1024 = 4/CU x 256 CU),
        // so every resident wave stays on the same level -> active table
        // working set is one 2 MB level (L2-resident per XCD)
        __syncthreads();
    }

#pragma unroll
    for (int p = 0; p < PPT; ++p) {
        floatx2 r; r.x = o0[p]; r.y = o1[p];
        __builtin_nontemporal_store(r, &out[t + p * TTHREADS]);
    }
}

// ---- fallback (R1 kernel) if ws_size is too small for the packed table ----
__global__ __launch_bounds__(256) void grid_fallback_kernel(
    const float* __restrict__ triplane,
    const float* __restrict__ inputs,
    float* __restrict__ out)
{
    const int i = blockIdx.x * blockDim.x + threadIdx.x;
    if (i >= NPOINTS) return;
    const float x0 = (inputs[3 * i + 0] + 1.0f) * 0.5f;
    const float y0 = (inputs[3 * i + 1] + 1.0f) * 0.5f;
    const float z0 = (inputs[3 * i + 2] + 1.0f) * 0.5f;
    float o0 = 0.0f, o1 = 0.0f;
#pragma unroll
    for (int level = 0; level < 3; ++level) {
        const float scale = (float)((128 << level) - 1);
        const float px = fmaf(x0, scale, 0.5f);
        const float py = fmaf(y0, scale, 0.5f);
        const float pz = fmaf(z0, scale, 0.5f);
        const float fx = floorf(px), fy = floorf(py), fz = floorf(pz);
        const float rx = px - fx, ry = py - fy, rz = pz - fz;
        const unsigned gx = (unsigned)fx, gy = (unsigned)fy, gz = (unsigned)fz;
        const float* __restrict__ base = triplane + level * (2 * PLANE);
#pragma unroll
        for (int c = 0; c < 8; ++c) {
            const unsigned bx = (c >> 0) & 1, by = (c >> 1) & 1, bz = (c >> 2) & 1;
            const unsigned h = (gx + bx) ^ ((gy + by) * 2654435761u) ^ ((gz + bz) * 805459861u);
            const unsigned local = h & HMASK;
            const float w = (bx ? rx : 1.0f - rx) * (by ? ry : 1.0f - ry) * (bz ? rz : 1.0f - rz);
            o0 = fmaf(w, base[local], o0);
            o1 = fmaf(w, base[PLANE + local], o1);
        }
    }
    reinterpret_cast<float2*>(out)[i] = make_float2(o0, o1);
}

extern "C" void kernel_launch(void* const* d_in, const int* in_sizes, int n_in,
                              void* d_out, int out_size, void* d_ws, size_t ws_size,
                              hipStream_t stream) {
    const float* triplane = (const float*)d_in[0];  // 3*2*1024*512 fp32
    const float* inputs   = (const float*)d_in[1];  // B*3 fp32
    const int threads = 256;

    if (ws_size >= (size_t)NTAB * sizeof(unsigned)) {
        unsigned* tbl = (unsigned*)d_ws;
        tp_convert_kernel<<<(NTAB / 4) / threads, threads, 0, stream>>>(
            triplane, (uintx4*)tbl);
        grid_gather_kernel<<<GBLOCKS, threads, 0, stream>>>(tbl, inputs, (floatx2*)d_out);
    } else {
        grid_fallback_kernel<<<NPOINTS / threads, threads, 0, stream>>>(
            triplane, inputs, (float*)d_out);
    }
}

// Round 3
// 624.189 us; speedup vs baseline: 1.0003x; 1.0003x over previous
//
#include <hip/hip_runtime.h>
#include <hip/hip_fp16.h>

// GridEncoder (instant-NGP triplane hash grid), static config:
//   D=3, L=3, C=2, base_res=128, per_level_scale=2, hashmap=2^19,
//   align_corners=False, linear interp, B=2^21.
// All levels hash-index; hmap=2^19 -> mod == & 0x7FFFF.
//
// R1: naive fp32 -> kernel 543 us, total 587 -> fixed harness overhead ~43.
// R2: half2 table + 3 level passes -> 62 us/pass @ 8 req/pt = 270 G req/s.
// R4: fused 24x4B -> 175 us.  R5: all-16B quads -> 184 us.
// R6/R7: mixed-width pair loads (15 req/pt floor for this layout class).
// R8: level-clustered fused gather, 2048 blocks x PPT=4, VGPR=108 ->
//     gather 127 us, FETCH 110 MB vs ~72 compulsory (two cohorts mix levels).
// R9: 1024 blocks x PPT=8 + __launch_bounds__(256,4): REGRESSION 590 us.
//     Allocator ignored the 128-VGPR headroom, targeted 8 waves/EU ->
//     VGPR=64 + scratch spills: WRITE_SIZE 16->707 MB, FETCH 0.11->1.02 GB.
// R10: pin occupancy with amdgpu_waves_per_eu(4,4) -> allocator budgets
//     128 VGPRs, no spill; 1024 blocks co-resident (4/CU), all waves on the
//     same level -> 2 MB active table set, L2-resident per XCD.

#define NPOINTS  2097152
#define HMASK    0x7FFFFu
#define PLANE    524288            // entries per level table
#define NTAB     (3 * PLANE)       // packed half2 entries (6 MB)
#define GBLOCKS  1024
#define TTHREADS (GBLOCKS * 256)   // 262144
#define PPT      8                 // points per thread

typedef float    floatx2 __attribute__((ext_vector_type(2)));
typedef float    floatx4 __attribute__((ext_vector_type(4)));
typedef unsigned uintx2  __attribute__((ext_vector_type(2)));
typedef unsigned uintx4  __attribute__((ext_vector_type(4)));

__device__ __forceinline__ unsigned pack2(float a, float b) {
    const __half2 h2 = __halves2half2(__float2half_rn(a), __float2half_rn(b));
    return *reinterpret_cast<const unsigned*>(&h2);
}

// ---- prepass: tbl[level*2^19 + h] = half2(b[h], b[PLANE+h]) ----
__global__ __launch_bounds__(256) void tp_convert_kernel(
    const float* __restrict__ tp, uintx4* __restrict__ tbl)
{
    const unsigned t = blockIdx.x * 256u + threadIdx.x;   // < NTAB/4
    const unsigned level = t >> 17;                       // 2^17 quads/level
    const unsigned i4    = (t & 131071u) << 2;
    const float* __restrict__ b = tp + level * (2u * PLANE);
    const floatx4 c0 = __builtin_nontemporal_load(
        reinterpret_cast<const floatx4*>(b + i4));
    const floatx4 c1 = __builtin_nontemporal_load(
        reinterpret_cast<const floatx4*>(b + PLANE + i4));
    uintx4 o;
    o.x = pack2(c0.x, c1.x);
    o.y = pack2(c0.y, c1.y);
    o.z = pack2(c0.z, c1.z);
    o.w = pack2(c0.w, c1.w);
    tbl[t] = o;
}

__device__ __forceinline__ unsigned sel4(uintx4 q, unsigned o) {
    const unsigned a = (o & 1u) ? q.y : q.x;
    const unsigned b = (o & 1u) ? q.w : q.z;
    return (o & 2u) ? b : a;
}

// ---- level-clustered fused gather, fully co-resident grid ----
__global__ __launch_bounds__(256)
__attribute__((amdgpu_waves_per_eu(4, 4)))
void grid_gather_kernel(
    const unsigned* __restrict__ tbl,
    const float* __restrict__ inputs,
    floatx2* __restrict__ out)
{
    const int t = blockIdx.x * 256 + threadIdx.x;

    float x0[PPT], y0[PPT], z0[PPT];
#pragma unroll
    for (int p = 0; p < PPT; ++p) {
        const int i = t + p * TTHREADS;
        const float x = __builtin_nontemporal_load(&inputs[3 * i + 0]);
        const float y = __builtin_nontemporal_load(&inputs[3 * i + 1]);
        const float z = __builtin_nontemporal_load(&inputs[3 * i + 2]);
        x0[p] = (x + 1.0f) * 0.5f;
        y0[p] = (y + 1.0f) * 0.5f;
        z0[p] = (z + 1.0f) * 0.5f;
    }

    float o0[PPT], o1[PPT];
#pragma unroll
    for (int p = 0; p < PPT; ++p) { o0[p] = 0.0f; o1[p] = 0.0f; }

#pragma unroll
    for (int level = 0; level < 3; ++level) {
        const float scale = (float)((128 << level) - 1);  // 127, 255, 511
        const unsigned lvl = (unsigned)level << 19;

#pragma unroll
        for (int p = 0; p < PPT; ++p) {
            const float px = fmaf(x0[p], scale, 0.5f);
            const float py = fmaf(y0[p], scale, 0.5f);
            const float pz = fmaf(z0[p], scale, 0.5f);
            const float fx = floorf(px), fy = floorf(py), fz = floorf(pz);
            const float rx = px - fx, ry = py - fy, rz = pz - fz;
            const unsigned gx = (unsigned)fx, gy = (unsigned)fy, gz = (unsigned)fz;

            const unsigned d = gx ^ (gx + 1u);            // 1,3,7,15,...
            const unsigned hy0 = gy * 2654435761u;
            const unsigned hy1 = (gy + 1u) * 2654435761u;
            const unsigned hz0 = gz * 805459861u;
            const unsigned hz1 = (gz + 1u) * 805459861u;

            unsigned P[4];
            P[0] = lvl | ((gx ^ hy0 ^ hz0) & HMASK);
            P[1] = lvl | ((gx ^ hy1 ^ hz0) & HMASK);
            P[2] = lvl | ((gx ^ hy0 ^ hz1) & HMASK);
            P[3] = lvl | ((gx ^ hy1 ^ hz1) & HMASK);

            // unconditional: aligned 16B quad containing e0 (and e1 if d<=3)
            uintx4 q[4];
#pragma unroll
            for (int j = 0; j < 4; ++j)
                q[j] = *reinterpret_cast<const uintx4*>(tbl + (P[j] & ~3u));

            // interp weights (VALU overlaps with loads in flight)
            const float wx1 = rx, wx0 = 1.0f - rx;
            const float wy1 = ry, wy0 = 1.0f - ry;
            const float wz1 = rz, wz0 = 1.0f - rz;
            const float wyz[4] = { wy0 * wz0, wy1 * wz0, wy0 * wz1, wy1 * wz1 };

            unsigned e1v[4];
            if (d > 3u) {
                // distant partner: 4B loads (same 64B line as quad for d<=15)
#pragma unroll
                for (int j = 0; j < 4; ++j) e1v[j] = tbl[P[j] ^ d];
            } else {
                // partner inside the quad
#pragma unroll
                for (int j = 0; j < 4; ++j) e1v[j] = sel4(q[j], (P[j] & 3u) ^ d);
            }

#pragma unroll
            for (int j = 0; j < 4; ++j) {
                const unsigned e0 = sel4(q[j], P[j] & 3u);
                const __half2 a = *reinterpret_cast<const __half2*>(&e0);
                const __half2 b = *reinterpret_cast<const __half2*>(&e1v[j]);
                const float2 fa = __half22float2(a);
                const float2 fb = __half22float2(b);
                const float wA = wx0 * wyz[j], wB = wx1 * wyz[j];
                o0[p] = fmaf(wA, fa.x, o0[p]); o1[p] = fmaf(wA, fa.y, o1[p]);
                o0[p] = fmaf(wB, fb.x, o0[p]); o1[p] = fmaf(wB, fb.y, o1[p]);
            }
        }
        // phase alignment: ALL blocks are co-resident (1024 = 4/CU x 256 CU),
        // so every resident wave stays on the same level -> active table
        // working set is one 2 MB level (L2-resident per XCD)
        __syncthreads();
    }

#pragma unroll
    for (int p = 0; p < PPT; ++p) {
        floatx2 r; r.x = o0[p]; r.y = o1[p];
        __builtin_nontemporal_store(r, &out[t + p * TTHREADS]);
    }
}

// ---- fallback (R1 kernel) if ws_size is too small for the packed table ----
__global__ __launch_bounds__(256) void grid_fallback_kernel(
    const float* __restrict__ triplane,
    const float* __restrict__ inputs,
    float* __restrict__ out)
{
    const int i = blockIdx.x * blockDim.x + threadIdx.x;
    if (i >= NPOINTS) return;
    const float x0 = (inputs[3 * i + 0] + 1.0f) * 0.5f;
    const float y0 = (inputs[3 * i + 1] + 1.0f) * 0.5f;
    const float z0 = (inputs[3 * i + 2] + 1.0f) * 0.5f;
    float o0 = 0.0f, o1 = 0.0f;
#pragma unroll
    for (int level = 0; level < 3; ++level) {
        const float scale = (float)((128 << level) - 1);
        const float px = fmaf(x0, scale, 0.5f);
        const float py = fmaf(y0, scale, 0.5f);
        const float pz = fmaf(z0, scale, 0.5f);
        const float fx = floorf(px), fy = floorf(py), fz = floorf(pz);
        const float rx = px - fx, ry = py - fy, rz = pz - fz;
        const unsigned gx = (unsigned)fx, gy = (unsigned)fy, gz = (unsigned)fz;
        const float* __restrict__ base = triplane + level * (2 * PLANE);
#pragma unroll
        for (int c = 0; c < 8; ++c) {
            const unsigned bx = (c >> 0) & 1, by = (c >> 1) & 1, bz = (c >> 2) & 1;
            const unsigned h = (gx + bx) ^ ((gy + by) * 2654435761u) ^ ((gz + bz) * 805459861u);
            const unsigned local = h & HMASK;
            const float w = (bx ? rx : 1.0f - rx) * (by ? ry : 1.0f - ry) * (bz ? rz : 1.0f - rz);
            o0 = fmaf(w, base[local], o0);
            o1 = fmaf(w, base[PLANE + local], o1);
        }
    }
    reinterpret_cast<float2*>(out)[i] = make_float2(o0, o1);
}

extern "C" void kernel_launch(void* const* d_in, const int* in_sizes, int n_in,
                              void* d_out, int out_size, void* d_ws, size_t ws_size,
                              hipStream_t stream) {
    const float* triplane = (const float*)d_in[0];  // 3*2*1024*512 fp32
    const float* inputs   = (const float*)d_in[1];  // B*3 fp32
    const int threads = 256;

    if (ws_size >= (size_t)NTAB * sizeof(unsigned)) {
        unsigned* tbl = (unsigned*)d_ws;
        tp_convert_kernel<<<(NTAB / 4) / threads, threads, 0, stream>>>(
            triplane, (uintx4*)tbl);
        grid_gather_kernel<<<GBLOCKS, threads, 0, stream>>>(tbl, inputs, (floatx2*)d_out);
    } else {
        grid_fallback_kernel<<<NPOINTS / threads, threads, 0, stream>>>(
            triplane, inputs, (float*)d_out);
    }
}

// Round 4
// 239.722 us; speedup vs baseline: 2.6047x; 2.6038x over previous
//
#include <hip/hip_runtime.h>
#include <hip/hip_fp16.h>

// GridEncoder (instant-NGP triplane hash grid), static config:
//   D=3, L=3, C=2, base_res=128, per_level_scale=2, hashmap=2^19,
//   align_corners=False, linear interp, B=2^21.
// All levels hash-index; hmap=2^19 -> mod == & 0x7FFFF.
//
// R1: naive fp32 -> kernel 543 us (total 587; fixed harness ~43 us).
// R2: half2 table + 3 level passes -> 62 us/pass @ 270 G req/s (L2-res).
// R4-R7: fused single-pass variants -> 15 req/pt floor, 127-184 us.
// R8: level-clustered fused, 2048 blk x PPT=4, VGPR=108, no scratch ->
//     gather 127 us, FETCH 110 MB vs ~72 compulsory (only 1024 of 2048
//     blocks co-resident -> two cohorts on different levels -> L2 thrash).
// R9/R10: PPT=8 single-group: alloca promotion FAILS (VGPR=64, arrays in
//     scratch, WRITE 707 MB, 558 us). waves_per_eu(4,4) did not fix it —
//     occupancy hints can't force mem2reg on an oversized unrolled nest.
// R11: 1024 blk x 256 thr x TWO sequential groups of PPT=4 points.
//     Per-group codegen identical to R8 (arrays scoped inside group loop
//     -> promoted, VGPR~108, 4 blk/CU) -> ALL 1024 blocks co-resident,
//     __syncthreads per level -> one 2 MB level table active at a time.

#define NPOINTS  2097152
#define HMASK    0x7FFFFu
#define PLANE    524288            // entries per level table
#define NTAB     (3 * PLANE)       // packed half2 entries (6 MB)
#define GBLOCKS  1024
#define TTHREADS (GBLOCKS * 256)   // 262144
#define PPT      4                 // points per group (R8-proven codegen)
#define NGROUPS  2                 // groups per thread: 2*4*262144 = 2^21

typedef float    floatx2 __attribute__((ext_vector_type(2)));
typedef float    floatx4 __attribute__((ext_vector_type(4)));
typedef unsigned uintx2  __attribute__((ext_vector_type(2)));
typedef unsigned uintx4  __attribute__((ext_vector_type(4)));

__device__ __forceinline__ unsigned pack2(float a, float b) {
    const __half2 h2 = __halves2half2(__float2half_rn(a), __float2half_rn(b));
    return *reinterpret_cast<const unsigned*>(&h2);
}

// ---- prepass: tbl[level*2^19 + h] = half2(b[h], b[PLANE+h]) ----
__global__ __launch_bounds__(256) void tp_convert_kernel(
    const float* __restrict__ tp, uintx4* __restrict__ tbl)
{
    const unsigned t = blockIdx.x * 256u + threadIdx.x;   // < NTAB/4
    const unsigned level = t >> 17;                       // 2^17 quads/level
    const unsigned i4    = (t & 131071u) << 2;
    const float* __restrict__ b = tp + level * (2u * PLANE);
    const floatx4 c0 = __builtin_nontemporal_load(
        reinterpret_cast<const floatx4*>(b + i4));
    const floatx4 c1 = __builtin_nontemporal_load(
        reinterpret_cast<const floatx4*>(b + PLANE + i4));
    uintx4 o;
    o.x = pack2(c0.x, c1.x);
    o.y = pack2(c0.y, c1.y);
    o.z = pack2(c0.z, c1.z);
    o.w = pack2(c0.w, c1.w);
    tbl[t] = o;
}

__device__ __forceinline__ unsigned sel4(uintx4 q, unsigned o) {
    const unsigned a = (o & 1u) ? q.y : q.x;
    const unsigned b = (o & 1u) ? q.w : q.z;
    return (o & 2u) ? b : a;
}

// ---- level-clustered fused gather, fully co-resident grid ----
__global__ __launch_bounds__(256) void grid_gather_kernel(
    const unsigned* __restrict__ tbl,
    const float* __restrict__ inputs,
    floatx2* __restrict__ out)
{
    const int t = blockIdx.x * 256 + threadIdx.x;

    for (int g = 0; g < NGROUPS; ++g) {
        const int base = t + g * (PPT * TTHREADS);

        float x0[PPT], y0[PPT], z0[PPT];
#pragma unroll
        for (int p = 0; p < PPT; ++p) {
            const int i = base + p * TTHREADS;
            const float x = __builtin_nontemporal_load(&inputs[3 * i + 0]);
            const float y = __builtin_nontemporal_load(&inputs[3 * i + 1]);
            const float z = __builtin_nontemporal_load(&inputs[3 * i + 2]);
            x0[p] = (x + 1.0f) * 0.5f;
            y0[p] = (y + 1.0f) * 0.5f;
            z0[p] = (z + 1.0f) * 0.5f;
        }

        float o0[PPT], o1[PPT];
#pragma unroll
        for (int p = 0; p < PPT; ++p) { o0[p] = 0.0f; o1[p] = 0.0f; }

#pragma unroll
        for (int level = 0; level < 3; ++level) {
            const float scale = (float)((128 << level) - 1);  // 127,255,511
            const unsigned lvl = (unsigned)level << 19;

#pragma unroll
            for (int p = 0; p < PPT; ++p) {
                const float px = fmaf(x0[p], scale, 0.5f);
                const float py = fmaf(y0[p], scale, 0.5f);
                const float pz = fmaf(z0[p], scale, 0.5f);
                const float fx = floorf(px), fy = floorf(py), fz = floorf(pz);
                const float rx = px - fx, ry = py - fy, rz = pz - fz;
                const unsigned gx = (unsigned)fx, gy = (unsigned)fy,
                               gz = (unsigned)fz;

                const unsigned d = gx ^ (gx + 1u);        // 1,3,7,15,...
                const unsigned hy0 = gy * 2654435761u;
                const unsigned hy1 = (gy + 1u) * 2654435761u;
                const unsigned hz0 = gz * 805459861u;
                const unsigned hz1 = (gz + 1u) * 805459861u;

                unsigned P[4];
                P[0] = lvl | ((gx ^ hy0 ^ hz0) & HMASK);
                P[1] = lvl | ((gx ^ hy1 ^ hz0) & HMASK);
                P[2] = lvl | ((gx ^ hy0 ^ hz1) & HMASK);
                P[3] = lvl | ((gx ^ hy1 ^ hz1) & HMASK);

                // aligned 16B quad containing e0 (and e1 when d<=3)
                uintx4 q[4];
#pragma unroll
                for (int j = 0; j < 4; ++j)
                    q[j] = *reinterpret_cast<const uintx4*>(tbl + (P[j] & ~3u));

                const float wx1 = rx, wx0 = 1.0f - rx;
                const float wy1 = ry, wy0 = 1.0f - ry;
                const float wz1 = rz, wz0 = 1.0f - rz;
                const float wyz[4] = { wy0 * wz0, wy1 * wz0,
                                       wy0 * wz1, wy1 * wz1 };

                unsigned e1v[4];
                if (d > 3u) {
                    // distant partner: 4B loads
#pragma unroll
                    for (int j = 0; j < 4; ++j) e1v[j] = tbl[P[j] ^ d];
                } else {
                    // partner inside the quad
#pragma unroll
                    for (int j = 0; j < 4; ++j)
                        e1v[j] = sel4(q[j], (P[j] & 3u) ^ d);
                }

#pragma unroll
                for (int j = 0; j < 4; ++j) {
                    const unsigned e0 = sel4(q[j], P[j] & 3u);
                    const __half2 a = *reinterpret_cast<const __half2*>(&e0);
                    const __half2 b = *reinterpret_cast<const __half2*>(&e1v[j]);
                    const float2 fa = __half22float2(a);
                    const float2 fb = __half22float2(b);
                    const float wA = wx0 * wyz[j], wB = wx1 * wyz[j];
                    o0[p] = fmaf(wA, fa.x, o0[p]); o1[p] = fmaf(wA, fa.y, o1[p]);
                    o0[p] = fmaf(wB, fb.x, o0[p]); o1[p] = fmaf(wB, fb.y, o1[p]);
                }
            }
            // keep all resident waves (ALL 1024 blocks: 4/CU x 256 CU) on the
            // same level -> active table set = one 2 MB level (L2-resident)
            __syncthreads();
        }

#pragma unroll
        for (int p = 0; p < PPT; ++p) {
            floatx2 r; r.x = o0[p]; r.y = o1[p];
            __builtin_nontemporal_store(r, &out[base + p * TTHREADS]);
        }
    }
}

// ---- fallback (R1 kernel) if ws_size is too small for the packed table ----
__global__ __launch_bounds__(256) void grid_fallback_kernel(
    const float* __restrict__ triplane,
    const float* __restrict__ inputs,
    float* __restrict__ out)
{
    const int i = blockIdx.x * blockDim.x + threadIdx.x;
    if (i >= NPOINTS) return;
    const float x0 = (inputs[3 * i + 0] + 1.0f) * 0.5f;
    const float y0 = (inputs[3 * i + 1] + 1.0f) * 0.5f;
    const float z0 = (inputs[3 * i + 2] + 1.0f) * 0.5f;
    float o0 = 0.0f, o1 = 0.0f;
#pragma unroll
    for (int level = 0; level < 3; ++level) {
        const float scale = (float)((128 << level) - 1);
        const float px = fmaf(x0, scale, 0.5f);
        const float py = fmaf(y0, scale, 0.5f);
        const float pz = fmaf(z0, scale, 0.5f);
        const float fx = floorf(px), fy = floorf(py), fz = floorf(pz);
        const float rx = px - fx, ry = py - fy, rz = pz - fz;
        const unsigned gx = (unsigned)fx, gy = (unsigned)fy, gz = (unsigned)fz;
        const float* __restrict__ base = triplane + level * (2 * PLANE);
#pragma unroll
        for (int c = 0; c < 8; ++c) {
            const unsigned bx = (c >> 0) & 1, by = (c >> 1) & 1, bz = (c >> 2) & 1;
            const unsigned h = (gx + bx) ^ ((gy + by) * 2654435761u) ^ ((gz + bz) * 805459861u);
            const unsigned local = h & HMASK;
            const float w = (bx ? rx : 1.0f - rx) * (by ? ry : 1.0f - ry) * (bz ? rz : 1.0f - rz);
            o0 = fmaf(w, base[local], o0);
            o1 = fmaf(w, base[PLANE + local], o1);
        }
    }
    reinterpret_cast<float2*>(out)[i] = make_float2(o0, o1);
}

extern "C" void kernel_launch(void* const* d_in, const int* in_sizes, int n_in,
                              void* d_out, int out_size, void* d_ws, size_t ws_size,
                              hipStream_t stream) {
    const float* triplane = (const float*)d_in[0];  // 3*2*1024*512 fp32
    const float* inputs   = (const float*)d_in[1];  // B*3 fp32
    const int threads = 256;

    if (ws_size >= (size_t)NTAB * sizeof(unsigned)) {
        unsigned* tbl = (unsigned*)d_ws;
        tp_convert_kernel<<<(NTAB / 4) / threads, threads, 0, stream>>>(
            triplane, (uintx4*)tbl);
        grid_gather_kernel<<<GBLOCKS, threads, 0, stream>>>(tbl, inputs, (floatx2*)d_out);
    } else {
        grid_fallback_kernel<<<NPOINTS / threads, threads, 0, stream>>>(
            triplane, inputs, (float*)d_out);
    }
}